// Round 6
// baseline (102.625 us; speedup 1.0000x reference)
//
#include <hip/hip_runtime.h>

#define O_ 2048
#define M_ 512
#define FIN 64
#define FMAS 64
#define DOUT 32
#define H_ 128
#define TD 96
#define NB_ 3

typedef __attribute__((ext_vector_type(4))) float f32x4;
typedef __attribute__((ext_vector_type(8))) short bf16x8;

__device__ __forceinline__ float elu_f(float x) {
    return x > 0.f ? x : (__expf(x) - 1.f);
}
// round-to-nearest-even f32 -> bf16
__device__ __forceinline__ unsigned short f2b(float x) {
    union { float f; unsigned u; } uu; uu.f = x;
    unsigned r = uu.u + 0x7fffu + ((uu.u >> 16) & 1u);
    return (unsigned short)(r >> 16);
}
__device__ __forceinline__ float b2f(unsigned short s) {
    union { float f; unsigned u; } uu; uu.u = ((unsigned)s) << 16;
    return uu.f;
}
// truncation split: x ~= hi + lo (each bf16), rem computed exactly
__device__ __forceinline__ void splitw(float x, short& h, short& lo) {
    unsigned u = __float_as_uint(x);
    unsigned short hi = (unsigned short)(u >> 16);
    float rem = x - b2f(hi);
    h = (short)hi;
    lo = (short)(unsigned short)(__float_as_uint(rem) >> 16);
}

// ---------------------------------------------------------------------------
// K0: scalars k_e, c_e and basis-combined relation weights Wt[f][t*32+e]
// ---------------------------------------------------------------------------
__global__ void k0_setup(const float* __restrict__ e_w1, const float* __restrict__ e_b1,
                         const float* __restrict__ e_w2, const float* __restrict__ e_b2,
                         const float* __restrict__ coeff, const float* __restrict__ v,
                         float* __restrict__ ws_scal, float* __restrict__ ws_wt) {
    __shared__ float r1[128], r2[128];
    const int t = threadIdx.x;
    r1[t] = e_w1[t] * e_w2[t];
    r2[t] = e_b1[t] * e_w2[t];
    __syncthreads();
    for (int s = 64; s > 0; s >>= 1) {
        if (t < s) { r1[t] += r1[t + s]; r2[t] += r2[t + s]; }
        __syncthreads();
    }
    if (t == 0) { ws_scal[0] = r1[0]; ws_scal[1] = r2[0] + e_b2[0]; }
    for (int idx = t; idx < FMAS * TD; idx += 128) {
        int f = idx / TD, te = idx % TD;
        int tt = te / DOUT, e = te % DOUT;
        float s = 0.f;
        for (int nb = 0; nb < NB_; ++nb)
            s += coeff[tt * NB_ + nb] * v[(nb * FMAS + f) * DOUT + e];
        ws_wt[idx] = s;
    }
}

// ---- G2 pipeline helpers (static indexing only) ----
__device__ __forceinline__ void g2_load(float4* pe, int4* pa,
        const float* __restrict__ f2base, const int* __restrict__ adb,
        long long aoff, int ks) {
    const float* fp0 = f2base + aoff + ks * 32;
    const int*   ap0 = adb    + aoff + ks * 32;
    pe[0] = *(const float4*)fp0;
    pe[1] = *(const float4*)(fp0 + 4);
    pa[0] = *(const int4*)ap0;
    pa[1] = *(const int4*)(ap0 + 4);
    pe[2] = *(const float4*)(fp0 + 16 * M_);
    pe[3] = *(const float4*)(fp0 + 16 * M_ + 4);
    pa[2] = *(const int4*)(ap0 + 16 * M_);
    pa[3] = *(const int4*)(ap0 + 16 * M_ + 4);
}

__device__ __forceinline__ void g2_step(const float4* pe, const int4* pa,
        f32x4 acc[2][4], const bf16x8* __restrict__ sHf,
        int l, int ks, float ke, float ce) {
    bf16x8 ah[2], al[2];
    #pragma unroll
    for (int rt = 0; rt < 2; ++rt) {
        #pragma unroll
        for (int h8 = 0; h8 < 2; ++h8) {
            float4 e4 = pe[rt * 2 + h8];
            int4   a4 = pa[rt * 2 + h8];
            short h, lo;
            splitw((a4.x == 1) ? fmaf(e4.x, ke, ce) : 0.f, h, lo);
            ah[rt][h8 * 4 + 0] = h; al[rt][h8 * 4 + 0] = lo;
            splitw((a4.y == 1) ? fmaf(e4.y, ke, ce) : 0.f, h, lo);
            ah[rt][h8 * 4 + 1] = h; al[rt][h8 * 4 + 1] = lo;
            splitw((a4.z == 1) ? fmaf(e4.z, ke, ce) : 0.f, h, lo);
            ah[rt][h8 * 4 + 2] = h; al[rt][h8 * 4 + 2] = lo;
            splitw((a4.w == 1) ? fmaf(e4.w, ke, ce) : 0.f, h, lo);
            ah[rt][h8 * 4 + 3] = h; al[rt][h8 * 4 + 3] = lo;
        }
    }
    #pragma unroll
    for (int ft = 0; ft < 4; ++ft) {
        bf16x8 b = sHf[(ft * 16 + ks) * 64 + l];
        acc[0][ft] = __builtin_amdgcn_mfma_f32_16x16x32_bf16(ah[0], b, acc[0][ft], 0, 0, 0);
        acc[0][ft] = __builtin_amdgcn_mfma_f32_16x16x32_bf16(al[0], b, acc[0][ft], 0, 0, 0);
        acc[1][ft] = __builtin_amdgcn_mfma_f32_16x16x32_bf16(ah[1], b, acc[1][ft], 0, 0, 0);
        acc[1][ft] = __builtin_amdgcn_mfma_f32_16x16x32_bf16(al[1], b, acc[1][ft], 0, 0, 0);
    }
}

// ---------------------------------------------------------------------------
// MEGA kernel: per block = 128 rows of one selected batch entry.
// 256 threads = 4 waves; wave w owns rows [w*32, w*32+32).
// Stage(W1,W2,H) -> sync -> G1 -> G2 (pipelined, no barrier between)
// -> sync -> stage(Wt,om1) -> sync -> G3/G4 + epilogue.
// MFMA frag conventions (validated R4/R5):
//   A: a[j]=A[c][g*8+j] ; B: b[j]=B[g*8+j][c] ; D: d[reg]=D[g*4+reg][c]
// ---------------------------------------------------------------------------
__global__ __launch_bounds__(256) void mega(
        const float* __restrict__ feat0, const float* __restrict__ feat2,
        const int* __restrict__ adj, const float* __restrict__ hmas,
        const int* __restrict__ bidx, const float* __restrict__ scal,
        const float* __restrict__ wt,
        const float* __restrict__ w0w1, const float* __restrict__ w0b1,
        const float* __restrict__ w0w2, const float* __restrict__ w0b2,
        const float* __restrict__ om1, const float* __restrict__ omb1,
        const float* __restrict__ om2v, const float* __restrict__ omb2,
        float* __restrict__ out) {
    __shared__ __align__(16) char poolW[90112];
    __shared__ __align__(16) char poolS[45056];
    __shared__ float sB1w0[128], sB2w0[32], sB1om[128], sOm2[128], sKe[4];

    const int t = threadIdx.x;
    const int l = t & 63, w = t >> 6;
    const int c = l & 15, g = l >> 4;
    const int tile = blockIdx.x;
    const int li = tile >> 4;
    const int o0 = (tile & 15) * 128;
    const int bi = bidx[li];

    if (t < 128) { sB1w0[t] = w0b1[t]; sB1om[t] = omb1[t]; sOm2[t] = om2v[t]; }
    if (t < 32) sB2w0[t] = w0b2[t];
    if (t == 0) { sKe[0] = scal[0]; sKe[1] = scal[1]; sKe[2] = omb2[0]; }

    // ---- stage G1 weights + G2's H, all before one sync ----
    bf16x8* sW1f = (bf16x8*)poolW;             // [8 nf][2 ks][64]
    bf16x8* sW2f = (bf16x8*)(poolW + 16384);   // [2 nf][4 ks][64]
    bf16x8* sHf  = (bf16x8*)(poolW + 24576);   // [4 ft][16 ks][64]
    for (int e = t; e < 1024; e += 256) {
        int nf = e >> 7, ks = (e >> 6) & 1, le = e & 63;
        int cc = le & 15, gg = le >> 4;
        bf16x8 vv;
        #pragma unroll
        for (int j = 0; j < 8; ++j)
            vv[j] = (short)f2b(w0w1[(ks * 32 + gg * 8 + j) * H_ + nf * 16 + cc]);
        sW1f[e] = vv;
    }
    for (int e = t; e < 512; e += 256) {
        int nf = e >> 8, ks = (e >> 6) & 3, le = e & 63;
        int cc = le & 15, gg = le >> 4;
        bf16x8 vv;
        #pragma unroll
        for (int j = 0; j < 8; ++j)
            vv[j] = (short)f2b(w0w2[(ks * 32 + gg * 8 + j) * DOUT + nf * 16 + cc]);
        sW2f[e] = vv;
    }
    const float* hbm = hmas + (long long)bi * M_ * FMAS;
    for (int e = t; e < 4096; e += 256) {
        int ft = e >> 10, ks = (e >> 6) & 15, le = e & 63;
        int cc = le & 15, gg = le >> 4;
        const float* src = hbm + (ks * 32 + gg * 8) * FMAS + ft * 16 + cc;
        bf16x8 vv;
        #pragma unroll
        for (int j = 0; j < 8; ++j) vv[j] = (short)f2b(src[j * FMAS]);
        sHf[e] = vv;
    }
    __syncthreads();

    // ---- G1: feat_opt = elu(feat0@W1+b1)@W2  (b2 added in epilogue) ----
    const float* f0b = feat0 + ((long long)bi * O_ + o0) * FIN;
    char* hidb = poolS + w * 11264;            // per-wave hidden scratch [32][272B]
    f32x4 fo[2][2];
    {
        f32x4 acc1[2][8];
        #pragma unroll
        for (int rf = 0; rf < 2; ++rf)
            #pragma unroll
            for (int nf = 0; nf < 8; ++nf) acc1[rf][nf] = (f32x4){0.f, 0.f, 0.f, 0.f};
        #pragma unroll
        for (int rf = 0; rf < 2; ++rf) {
            #pragma unroll
            for (int ks = 0; ks < 2; ++ks) {
                const float* ap = f0b + (w * 32 + rf * 16 + c) * FIN + ks * 32 + g * 8;
                float4 x0 = *(const float4*)ap;
                float4 x1 = *(const float4*)(ap + 4);
                bf16x8 a;
                a[0] = (short)f2b(x0.x); a[1] = (short)f2b(x0.y);
                a[2] = (short)f2b(x0.z); a[3] = (short)f2b(x0.w);
                a[4] = (short)f2b(x1.x); a[5] = (short)f2b(x1.y);
                a[6] = (short)f2b(x1.z); a[7] = (short)f2b(x1.w);
                #pragma unroll
                for (int nf = 0; nf < 8; ++nf)
                    acc1[rf][nf] = __builtin_amdgcn_mfma_f32_16x16x32_bf16(
                        a, sW1f[(nf * 2 + ks) * 64 + l], acc1[rf][nf], 0, 0, 0);
            }
        }
        #pragma unroll
        for (int rf = 0; rf < 2; ++rf)
            #pragma unroll
            for (int nf = 0; nf < 8; ++nf)
                #pragma unroll
                for (int reg = 0; reg < 4; ++reg) {
                    int row = rf * 16 + g * 4 + reg;
                    float hv = acc1[rf][nf][reg] + sB1w0[nf * 16 + c];
                    *(unsigned short*)(hidb + row * 272 + (nf * 16 + c) * 2) =
                        f2b(elu_f(hv));
                }
        #pragma unroll
        for (int rf = 0; rf < 2; ++rf)
            #pragma unroll
            for (int nf2 = 0; nf2 < 2; ++nf2) fo[rf][nf2] = (f32x4){0.f, 0.f, 0.f, 0.f};
        #pragma unroll
        for (int rf = 0; rf < 2; ++rf)
            #pragma unroll
            for (int ks = 0; ks < 4; ++ks) {
                bf16x8 a = *(const bf16x8*)(hidb + (rf * 16 + c) * 272 + ks * 64 + g * 16);
                #pragma unroll
                for (int nf2 = 0; nf2 < 2; ++nf2)
                    fo[rf][nf2] = __builtin_amdgcn_mfma_f32_16x16x32_bf16(
                        a, sW2f[(nf2 * 4 + ks) * 64 + l], fo[rf][nf2], 0, 0, 0);
            }
    }
    // NO barrier: G2 reads sHf (staged before first sync); G1 scratch is wave-private.

    // ---- G2: agg = (mask*(ke*feat2+ce)) @ H, 3-deep pipelined ----
    const float ke = sKe[0], ce = sKe[1];
    const float* f2base = feat2 + ((long long)bi * O_ + o0) * M_;
    const int*   adb    = adj   + ((long long)bi * O_ + o0) * M_;
    f32x4 acc[2][4];
    #pragma unroll
    for (int rt = 0; rt < 2; ++rt)
        #pragma unroll
        for (int ft = 0; ft < 4; ++ft) acc[rt][ft] = (f32x4){0.f, 0.f, 0.f, 0.f};
    const long long aoff = (long long)(w * 32 + c) * M_ + 8 * g;
    {
        float4 peA[4], peB[4];
        int4   paA[4], paB[4];
        g2_load(peA, paA, f2base, adb, aoff, 0);
        g2_load(peB, paB, f2base, adb, aoff, 1);
        #pragma unroll
        for (int ks = 0; ks < 16; ks += 2) {
            g2_step(peA, paA, acc, sHf, l, ks, ke, ce);
            if (ks + 2 < 16) g2_load(peA, paA, f2base, adb, aoff, ks + 2);
            g2_step(peB, paB, acc, sHf, l, ks + 1, ke, ce);
            if (ks + 3 < 16) g2_load(peB, paB, f2base, adb, aoff, ks + 3);
        }
    }
    __syncthreads();   // all waves done with sHf / sW1f regions

    // ---- stage G3/G4 weights (hi/lo bf16 fragment order) ----
    bf16x8* sWtH = (bf16x8*)poolW;             // [6 nf][2 ks][64]
    bf16x8* sWtL = (bf16x8*)(poolW + 12288);
    bf16x8* sO1H = (bf16x8*)(poolW + 24576);   // [8 nf][3 ks][64]
    bf16x8* sO1L = (bf16x8*)(poolW + 49152);
    for (int e = t; e < 768; e += 256) {
        int nf = e >> 7, ks = (e >> 6) & 1, le = e & 63;
        int cc = le & 15, gg = le >> 4;
        bf16x8 vh, vl;
        #pragma unroll
        for (int j = 0; j < 8; ++j) {
            float vv = wt[(ks * 32 + gg * 8 + j) * TD + nf * 16 + cc];
            short h, lo; splitw(vv, h, lo);
            vh[j] = h; vl[j] = lo;
        }
        sWtH[e] = vh; sWtL[e] = vl;
    }
    for (int e = t; e < 1536; e += 256) {
        int nf = e / 192, r = e % 192, ks = r >> 6, le = r & 63;
        int cc = le & 15, gg = le >> 4;
        bf16x8 vh, vl;
        #pragma unroll
        for (int j = 0; j < 8; ++j) {
            float vv = om1[(ks * 32 + gg * 8 + j) * H_ + nf * 16 + cc];
            short h, lo; splitw(vv, h, lo);
            vh[j] = h; vl[j] = lo;
        }
        sO1H[e] = vh; sO1L[e] = vl;
    }
    __syncthreads();

    // ---- G3/G4 + epilogue, two 16-row passes per wave (per-wave scratch) ----
    char* Sw   = poolS + w * 11264;
    char* aggH = Sw;            // [16][144B]
    char* aggL = Sw + 2304;
    char* tyH  = Sw + 4608;     // [16][208B]
    char* tyL  = Sw + 7936;
    const float ob2 = sKe[2];
    const long long orow0 = (long long)li * O_ + o0 + w * 32;

    #pragma unroll
    for (int rf = 0; rf < 2; ++rf) {
        #pragma unroll
        for (int ft = 0; ft < 4; ++ft)
            #pragma unroll
            for (int reg = 0; reg < 4; ++reg) {
                int row = g * 4 + reg;
                float vv = acc[rf][ft][reg];
                short h, lo; splitw(vv, h, lo);
                *(short*)(aggH + row * 144 + (ft * 16 + c) * 2) = h;
                *(short*)(aggL + row * 144 + (ft * 16 + c) * 2) = lo;
            }
        f32x4 ty[6];
        #pragma unroll
        for (int nf = 0; nf < 6; ++nf) ty[nf] = (f32x4){0.f, 0.f, 0.f, 0.f};
        #pragma unroll
        for (int ks = 0; ks < 2; ++ks) {
            bf16x8 aH = *(const bf16x8*)(aggH + c * 144 + ks * 64 + g * 16);
            bf16x8 aL = *(const bf16x8*)(aggL + c * 144 + ks * 64 + g * 16);
            #pragma unroll
            for (int nf = 0; nf < 6; ++nf) {
                bf16x8 bH = sWtH[(nf * 2 + ks) * 64 + l];
                bf16x8 bL = sWtL[(nf * 2 + ks) * 64 + l];
                ty[nf] = __builtin_amdgcn_mfma_f32_16x16x32_bf16(aH, bH, ty[nf], 0, 0, 0);
                ty[nf] = __builtin_amdgcn_mfma_f32_16x16x32_bf16(aL, bH, ty[nf], 0, 0, 0);
                ty[nf] = __builtin_amdgcn_mfma_f32_16x16x32_bf16(aH, bL, ty[nf], 0, 0, 0);
            }
        }
        #pragma unroll
        for (int nf = 0; nf < 6; ++nf)
            #pragma unroll
            for (int reg = 0; reg < 4; ++reg) {
                int row = g * 4 + reg;
                float vv = ty[nf][reg];
                short h, lo; splitw(vv, h, lo);
                *(short*)(tyH + row * 208 + (nf * 16 + c) * 2) = h;
                *(short*)(tyL + row * 208 + (nf * 16 + c) * 2) = lo;
            }
        f32x4 h2[8];
        #pragma unroll
        for (int nf = 0; nf < 8; ++nf) h2[nf] = (f32x4){0.f, 0.f, 0.f, 0.f};
        #pragma unroll
        for (int ks = 0; ks < 3; ++ks) {
            bf16x8 aH = *(const bf16x8*)(tyH + c * 208 + ks * 64 + g * 16);
            bf16x8 aL = *(const bf16x8*)(tyL + c * 208 + ks * 64 + g * 16);
            #pragma unroll
            for (int nf = 0; nf < 8; ++nf) {
                bf16x8 bH = sO1H[(nf * 3 + ks) * 64 + l];
                bf16x8 bL = sO1L[(nf * 3 + ks) * 64 + l];
                h2[nf] = __builtin_amdgcn_mfma_f32_16x16x32_bf16(aH, bH, h2[nf], 0, 0, 0);
                h2[nf] = __builtin_amdgcn_mfma_f32_16x16x32_bf16(aL, bH, h2[nf], 0, 0, 0);
                h2[nf] = __builtin_amdgcn_mfma_f32_16x16x32_bf16(aH, bL, h2[nf], 0, 0, 0);
            }
        }
        float p[4] = {0.f, 0.f, 0.f, 0.f};
        #pragma unroll
        for (int nf = 0; nf < 8; ++nf) {
            float o2 = sOm2[nf * 16 + c];
            float bb = sB1om[nf * 16 + c];
            #pragma unroll
            for (int reg = 0; reg < 4; ++reg)
                p[reg] += elu_f(h2[nf][reg] + bb) * o2;
        }
        #pragma unroll
        for (int reg = 0; reg < 4; ++reg) {
            #pragma unroll
            for (int off = 1; off < 16; off <<= 1)
                p[reg] += __shfl_xor(p[reg], off, 64);
            p[reg] += ob2;
        }
        #pragma unroll
        for (int nf2 = 0; nf2 < 2; ++nf2) {
            float b2v = sB2w0[nf2 * 16 + c];
            #pragma unroll
            for (int reg = 0; reg < 4; ++reg) {
                long long orow = orow0 + rf * 16 + g * 4 + reg;
                float val = fo[rf][nf2][reg] + b2v + p[reg];
                val = val >= 0.f ? val : 0.2f * val;
                out[orow * DOUT + nf2 * 16 + c] = val;
            }
        }
    }
}

// ---------------------------------------------------------------------------
extern "C" void kernel_launch(void* const* d_in, const int* in_sizes, int n_in,
                              void* d_out, int out_size, void* d_ws, size_t ws_size,
                              hipStream_t stream) {
    const float* feat0 = (const float*)d_in[0];
    const float* feat1 = (const float*)d_in[1];
    const float* feat2 = (const float*)d_in[2];
    const int*   adj   = (const int*)d_in[3];
    const int*   bidx  = (const int*)d_in[4];
    const float* w0_w1 = (const float*)d_in[5];
    const float* w0_b1 = (const float*)d_in[6];
    const float* w0_w2 = (const float*)d_in[7];
    const float* w0_b2 = (const float*)d_in[8];
    const float* v     = (const float*)d_in[9];
    const float* coeff = (const float*)d_in[10];
    const float* e_w1  = (const float*)d_in[11];
    const float* e_b1  = (const float*)d_in[12];
    const float* e_w2  = (const float*)d_in[13];
    const float* e_b2  = (const float*)d_in[14];
    const float* om_w1 = (const float*)d_in[15];
    const float* om_b1 = (const float*)d_in[16];
    const float* om_w2 = (const float*)d_in[17];
    const float* om_b2 = (const float*)d_in[18];
    float* out = (float*)d_out;
    float* ws  = (float*)d_ws;

    const int bsel = in_sizes[4];          // 32
    float* ws_scal = ws;                   // 2 floats
    float* ws_wt   = ws + 16;              // 64*96 floats

    k0_setup<<<1, 128, 0, stream>>>(e_w1, e_b1, e_w2, e_b2, coeff, v, ws_scal, ws_wt);
    mega<<<bsel * 16, 256, 0, stream>>>(feat0, feat2, adj, feat1, bidx,
                                        ws_scal, ws_wt,
                                        w0_w1, w0_b1, w0_w2, w0_b2,
                                        om_w1, om_b1, om_w2, om_b2, out);
}